// Round 11
// baseline (184.331 us; speedup 1.0000x reference)
//
#include <hip/hip_runtime.h>

// DynamicRouting (CapsNet) on MI355X — R16: the U-pass (channel-reduce) is
// rebuilt as a CONTIGUOUS-STREAM kernel; iteration 0 becomes its own small
// kernel. D=4 (dispatch count is free: measured model dur ~= 55us fill +
// ~44us fixed graph cost + sum(kernels); R8/R10's measured fused kernels
// pin the fixed cost at ~44 regardless of D).
// B=16, I=32, C=8, J=10, D=16, H=W=6 -> DHW=576. num_routing=3 (fixed).
//
// R15 post-mortem: a1 already had 8 loads in flight (compiler batches the
// c-loads); 16-in-flight changed nothing (-1.4us). a1 is NOT latency/
// concurrency-bound -> pattern-bound: 160 blocks x 8 channel-streams at
// 5.76KB stride = ~1280 strided streams (2.3KB runs) thrash HBM pages;
// the harness fill (contiguous per wave) hits 6.8TB/s on the same chip.
//
// R16 uw_kernel: block = (b,i) [512 blocks, all 256 CUs, 2/CU]; for fixed
// (b,i), u_hat[b,i,c,:,:] is a CONTIGUOUS 184KB span. c-outer loop sweeps
// 8 sequential contiguous 23KB windows per block; acc[6] registers hold the
// running sum (order 0+c0+..+c7 per element = R14's chain, bit-identical).
// U2 re-laid out as [b][i][1440]f4 so writes are contiguous as well.
// it0/ab1/final are R14-verbatim chains with only the U2 address map
// updated (values identical; R14 passed, absmax 3.814697e-06).
// No atomics, no spins, no memsets; poison-safe (ws written before read).

#define NB   16
#define NI   32
#define NC   8
#define NJ   10
#define ND   16
#define NHW  36
#define NDHW 576
#define NBJ  (NB * NJ)             // 160
#define NTOT (NB * NJ * NDHW)      // 92160
#define EPSV 1e-7f
#define TPB  576                   // 9 waves; one thread per dhw
#define UWB  256                   // uw threads
// U2 float strides: [b][i][j*576+dhw] -> (b*NI+i)*5760 + j*576 + dhw
#define U2_I 5760
// transposed partial strides (doubles)
#define GP_ITER (NJ * NI * NB)     // 5120  Gp_t[rr][j][i][b]
#define GP_J    (NI * NB)          // 512
#define GP_I    (NB)               // 16
#define N1_ITER (NB * NJ)          // 160   n1p_t[rr][b][j]
#define N1_B    (NJ)               // 10

static __device__ __forceinline__ double wave_sum(double v) {
    #pragma unroll
    for (int off = 32; off > 0; off >>= 1) v += __shfl_down(v, off);
    return v;
}

// block-reduce |sv| over 576 threads -> slot (thread 0 writes one double)
static __device__ __forceinline__ void n1_reduce(float sv, double* slot,
                                                 double* nred /*[9]*/) {
    int tid = threadIdx.x;
    double a = wave_sum((double)fabsf(sv));
    if ((tid & 63) == 0) nred[tid >> 6] = a;
    __syncthreads();
    if (tid == 0) {
        double t = nred[0];
        #pragma unroll
        for (int w = 1; w < 9; ++w) t += nred[w];
        *slot = t;
    }
}

// block-reduce Uv[i]*sv over 576 threads; transposed store gbase[i*GP_I]
static __device__ __forceinline__ void g_reduce_t(const float* Uv, float sv,
                                                  double* gbase,
                                                  double (*gred)[32] /*[9][32]*/) {
    int tid = threadIdx.x, w = tid >> 6, lane = tid & 63;
    #pragma unroll
    for (int i = 0; i < NI; ++i) {
        double p = wave_sum((double)Uv[i] * (double)sv);
        if (lane == 0) gred[w][i] = p;
    }
    __syncthreads();
    if (tid < NI) {
        double t = gred[0][tid];
        #pragma unroll
        for (int w2 = 1; w2 < 9; ++w2) t += gred[w2][tid];
        gbase[tid * GP_I] = t;
    }
}

// ---------------------------------------------------------------------------
// UW kernel: U[b,i,:] = sum_c u_hat[b,i,c,:]. One block per (b,i); the
// block's input (8 x 1440 float4) is ONE contiguous 184KB span, swept as
// 8 sequential contiguous 23KB windows (c-outer). Writes contiguous.
// ---------------------------------------------------------------------------
__global__ __launch_bounds__(UWB) void uw_kernel(
    const float4* __restrict__ uh4, float4* __restrict__ U2f4)
{
    const int blk = blockIdx.x;            // b*NI + i
    const int tid = threadIdx.x;
    const float4* in  = uh4 + (size_t)blk * (NC * 1440);
    float4*       out = U2f4 + (size_t)blk * 1440;

    float4 acc[6];
    #pragma unroll
    for (int r = 0; r < 6; ++r) acc[r] = make_float4(0.f, 0.f, 0.f, 0.f);

    #pragma unroll
    for (int c = 0; c < NC; ++c) {
        const float4* pc = in + c * 1440;
        float4 v[6];
        #pragma unroll
        for (int r = 0; r < 6; ++r) {
            int o = r * UWB + tid;
            if (o < 1440) v[r] = pc[o];    // contiguous 23KB window
        }
        #pragma unroll
        for (int r = 0; r < 6; ++r) {
            int o = r * UWB + tid;
            if (o < 1440) {                // element order: 0 + c0 + ... + c7
                acc[r].x += v[r].x; acc[r].y += v[r].y;
                acc[r].z += v[r].z; acc[r].w += v[r].w;
            }
        }
    }
    #pragma unroll
    for (int r = 0; r < 6; ++r) {
        int o = r * UWB + tid;
        if (o < 1440) out[o] = acc[r];
    }
}

// ---------------------------------------------------------------------------
// IT0 kernel = routing iteration 0 (c == 0.1). One block per (b,j), 576 thr.
// Reads the L2/L3-resident U2; same arithmetic chain as R14's a1 phase 2.
// ---------------------------------------------------------------------------
__global__ __launch_bounds__(TPB) void it0_kernel(
    const float* __restrict__ U2, const float* __restrict__ bias,
    double* __restrict__ n1p, double* __restrict__ Gp)
{
    __shared__ double nred[9];
    __shared__ double gred[9][32];

    const int blk = blockIdx.x;            // b*NJ + j
    const int b = blk / NJ, j = blk - b * NJ;
    const int tid = threadIdx.x;           // dhw

    const float* u2b = U2 + (size_t)(b * NI) * U2_I + j * NDHW + tid;
    const float cw = 1.0f / 10.0f;
    float Uv[NI];
    float sv = bias[j * ND + tid / NHW];
    #pragma unroll
    for (int i = 0; i < NI; ++i) {
        Uv[i] = u2b[(size_t)i * U2_I];
        sv += cw * Uv[i];
    }

    n1_reduce(sv, &n1p[b * N1_B + j], nred);
    g_reduce_t(Uv, sv, Gp + j * GP_J + b, gred);
}

// ---------------------------------------------------------------------------
// Kernel AB1 = routing iteration 1. One block per (b,j), 576 threads.
// R14-verbatim; only the U2 address map changed.
// ---------------------------------------------------------------------------
__global__ __launch_bounds__(TPB) void ab1_kernel(
    const float* __restrict__ U2, const float* __restrict__ bias,
    double* __restrict__ n1p, double* __restrict__ Gp)
{
    __shared__ double sc_sh[NB];
    __shared__ float  bij_sh[NI * NJ];
    __shared__ float  c_sh[NI];
    __shared__ double nred[9];
    __shared__ double gred[9][32];

    const int blk = blockIdx.x;            // b*NJ + j
    const int b = blk / NJ, j = blk - b * NJ;
    const int tid = threadIdx.x;

    // sc[bb]: 10 contiguous doubles (jj 0..9 — R5 order)
    if (tid < NB) {
        const double* np = n1p + tid * N1_B;
        double n1 = 0.0;
        #pragma unroll
        for (int jj = 0; jj < NJ; ++jj) n1 += np[jj];
        double nsq = n1 * n1;
        sc_sh[tid] = (nsq / (1.0 + nsq)) / (n1 + (double)EPSV);
    }
    __syncthreads();

    // b_ij[i,jj]: 16 contiguous doubles per entry (bb 0..15 — R5 order)
    if (tid < NI * NJ) {
        int i = tid / NJ, jj = tid - i * NJ;
        const double* g = Gp + jj * GP_J + i * GP_I;
        double a = 0.0;
        #pragma unroll
        for (int bb = 0; bb < NB; ++bb) a += sc_sh[bb] * g[bb];
        bij_sh[tid] = (float)a;
    }
    __syncthreads();

    // softmax rows -> c[:, j]
    if (tid < NI) {
        float m = -1e30f;
        #pragma unroll
        for (int jj = 0; jj < NJ; ++jj) m = fmaxf(m, bij_sh[tid * NJ + jj]);
        float sum = 0.f;
        #pragma unroll
        for (int jj = 0; jj < NJ; ++jj) sum += expf(bij_sh[tid * NJ + jj] - m);
        c_sh[tid] = expf(bij_sh[tid * NJ + j] - m) / sum;
    }
    __syncthreads();

    // s pass
    const float* u2b = U2 + (size_t)(b * NI) * U2_I + j * NDHW + tid;
    float Uv[NI];
    float sv = bias[j * ND + tid / NHW];
    #pragma unroll
    for (int i = 0; i < NI; ++i) {
        Uv[i] = u2b[(size_t)i * U2_I];
        sv += c_sh[i] * Uv[i];
    }

    n1_reduce(sv, &n1p[N1_ITER + b * N1_B + j], nred);
    g_reduce_t(Uv, sv, Gp + GP_ITER + j * GP_J + b, gred);
}

// ---------------------------------------------------------------------------
// FINAL kernel = routing iteration 2 + squash + output. 160 blocks x 576.
// XCD-SWIZZLED mapping: blk = j*NB + b (siblings of one b congruent mod 8
// -> co-located on one XCD; their 10x redundant U2[b] read stays in its L2).
// R14-verbatim; only the U2 address map changed.
// ---------------------------------------------------------------------------
__global__ __launch_bounds__(TPB) void final_kernel(
    const float* __restrict__ U2, const float* __restrict__ bias,
    const double* __restrict__ n1p, const double* __restrict__ Gp,
    float* __restrict__ out)
{
    __shared__ double sc_sh[2][NB];
    __shared__ float  bij_sh[NI * NJ];
    __shared__ float  c_sh[NI * NJ];
    __shared__ double nred[9];
    __shared__ double n1_sh;

    const int blk = blockIdx.x;            // j*NB + b (swizzled)
    const int b = blk & (NB - 1), j = blk >> 4;
    const int tid = threadIdx.x;           // dhw

    // sc for iterations 0 and 1 (10 contiguous doubles each; R5 order)
    if (tid < 2 * NB) {
        int rr = tid >> 4, bb = tid & 15;
        const double* np = n1p + rr * N1_ITER + bb * N1_B;
        double n1 = 0.0;
        #pragma unroll
        for (int jj = 0; jj < NJ; ++jj) n1 += np[jj];
        double nsq = n1 * n1;
        sc_sh[rr][bb] = (nsq / (1.0 + nsq)) / (n1 + (double)EPSV);
    }
    __syncthreads();

    // b_ij[i,jj] over both iterations (rr outer, bb 0..15 — R5 ab<2> order)
    if (tid < NI * NJ) {
        int i = tid / NJ, jj = tid - i * NJ;
        double a = 0.0;
        for (int rr = 0; rr < 2; ++rr) {
            const double* g = Gp + rr * GP_ITER + jj * GP_J + i * GP_I;
            #pragma unroll
            for (int bb = 0; bb < NB; ++bb) a += sc_sh[rr][bb] * g[bb];
        }
        bij_sh[tid] = (float)a;
    }
    __syncthreads();

    // softmax: c[i,jj] for ALL jj (same per-row m/sum chains as R5)
    if (tid < NI * NJ) {
        int i = tid / NJ;
        float m = -1e30f;
        #pragma unroll
        for (int j2 = 0; j2 < NJ; ++j2) m = fmaxf(m, bij_sh[i * NJ + j2]);
        float sum = 0.f;
        #pragma unroll
        for (int j2 = 0; j2 < NJ; ++j2) sum += expf(bij_sh[i * NJ + j2] - m);
        c_sh[tid] = expf(bij_sh[tid] - m) / sum;
    }
    __syncthreads();

    // s for all jj at this thread's dhw; fold |s| locally; keep own j's s.
    const float* ub = U2 + (size_t)(b * NI) * U2_I + tid;
    const int drow = tid / NHW;
    double t = 0.0;
    float sv_out = 0.f;
    #pragma unroll 1                       // sequential jj: bounded VGPR use
    for (int jj = 0; jj < NJ; ++jj) {
        const float* up = ub + jj * NDHW;
        float sv = bias[jj * ND + drow];
        #pragma unroll                     // 32 coalesced loads in flight
        for (int i = 0; i < NI; ++i) sv += c_sh[i * NJ + jj] * up[(size_t)i * U2_I];
        t += (double)fabsf(sv);
        if (jj == j) sv_out = sv;          // predicated, no runtime indexing
    }

    // n1(b): 9-wave tree over per-thread partials (deterministic; identical
    // across the 10 sibling blocks of this b)
    double a = wave_sum(t);
    if ((tid & 63) == 0) nred[tid >> 6] = a;
    __syncthreads();
    if (tid == 0) {
        double n1 = nred[0];
        #pragma unroll
        for (int w = 1; w < 9; ++w) n1 += nred[w];
        n1_sh = n1;
    }
    __syncthreads();

    // squash + store own j (R5 v_kernel float exprs verbatim)
    float n1f = (float)n1_sh;
    float nsq = n1f * n1f;
    out[(size_t)(b * NJ + j) * NDHW + tid] =
        (nsq / (1.f + nsq)) * (sv_out / (n1f + EPSV));
}

extern "C" void kernel_launch(void* const* d_in, const int* in_sizes, int n_in,
                              void* d_out, int out_size, void* d_ws, size_t ws_size,
                              hipStream_t stream)
{
    const float* u_hat = (const float*)d_in[0];
    const float* bias  = (const float*)d_in[1];
    float* out = (float*)d_out;
    // d_in[2] = num_routing, fixed at 3 by the problem.

    // Workspace layout (8B aligned):
    //   U2  : 2,949,120 floats (11.8 MB)   [b][i][j*576+dhw]
    //   n1p : 2*160 doubles                n1p_t[rr][b][j]
    //   Gp  : 2*5120 doubles (82 KB)       Gp_t[rr][j][i][b]
    float*  U2  = (float*)d_ws;
    double* n1p = (double*)(U2 + (size_t)NB * NJ * NI * NDHW);
    double* Gp  = n1p + 2 * N1_ITER;

    uw_kernel<<<NB * NI, UWB, 0, stream>>>(
        (const float4*)u_hat, (float4*)U2);
    it0_kernel<<<NBJ, TPB, 0, stream>>>(U2, bias, n1p, Gp);
    ab1_kernel<<<NBJ, TPB, 0, stream>>>(U2, bias, n1p, Gp);
    final_kernel<<<NBJ, TPB, 0, stream>>>(U2, bias, n1p, Gp, out);
}